// Round 2
// baseline (3250.238 us; speedup 1.0000x reference)
//
#include <hip/hip_runtime.h>
#include <stdint.h>

#define NLAYERS 6
#define DMODEL  512
#define NHEADS  8
#define HDIM    64
#define INNER   2048
#define SEQ     128
#define BATCH   256
#define NTOK    (BATCH*SEQ)

typedef __attribute__((ext_vector_type(4))) float f32x4;
typedef __attribute__((ext_vector_type(8))) _Float16 hfrag;

typedef const __attribute__((address_space(1))) void* gas1p;
typedef __attribute__((address_space(3))) void* las3p;

__device__ __forceinline__ void load_lds16(const void* g, void* l) {
  __builtin_amdgcn_global_load_lds((gas1p)(uintptr_t)g, (las3p)(uint32_t)(uintptr_t)l, 16, 0, 0);
}

__device__ __forceinline__ ushort f2h(float f) {
  return __builtin_bit_cast(ushort, (_Float16)f);
}

__device__ __forceinline__ f32x4 mfma16(hfrag a, hfrag b, f32x4 c) {
  return __builtin_amdgcn_mfma_f32_16x16x32_f16(a, b, c, 0, 0, 0);
}

// ---------------- weight prep (f32 -> f16, transposed to [N][K]) ----------------

__global__ void prep_qkv(const float* __restrict__ Wq, const float* __restrict__ Wk,
                         const float* __restrict__ Wv, const float* __restrict__ bq,
                         const float* __restrict__ bk, const float* __restrict__ bv,
                         ushort* __restrict__ Wt, float* __restrict__ biasq) {
  int idx = blockIdx.x*256 + threadIdx.x;
  if (idx >= NLAYERS*1536*512) return;
  const int k = idx & 511;
  const int n = (idx >> 9) % 1536;
  const int l = idx / (1536*512);
  const int which = n >> 9, hh = (n >> 6) & 7, e = n & 63;
  const float* W = (which == 0) ? Wq : ((which == 1) ? Wk : Wv);
  Wt[idx] = f2h(W[(((size_t)l*NHEADS + hh)*DMODEL + k)*HDIM + e]);
  if (k == 0) {
    const float* bb = (which == 0) ? bq : ((which == 1) ? bk : bv);
    biasq[l*1536 + n] = bb[((size_t)l*NHEADS + hh)*HDIM + e];
  }
}

__global__ void prep_w1(const float* __restrict__ W1, ushort* __restrict__ W1t) {
  int idx = blockIdx.x*256 + threadIdx.x;
  if (idx >= NLAYERS*INNER*512) return;
  const int k = idx & 511;
  const int n = (idx >> 9) % INNER;
  const int l = idx / (INNER*512);
  W1t[idx] = f2h(W1[((size_t)l*DMODEL + k)*INNER + n]);
}

__global__ void prep_w2(const float* __restrict__ W2, ushort* __restrict__ W2t) {
  int idx = blockIdx.x*256 + threadIdx.x;
  if (idx >= NLAYERS*512*INNER) return;
  const int k = idx & 2047;
  const int n = (idx >> 11) & 511;
  const int l = idx / (512*INNER);
  W2t[idx] = f2h(W2[((size_t)l*INNER + k)*DMODEL + n]);
}

// ---------------- embedding + positional encoding ----------------

__global__ void embed_kernel(const int* __restrict__ x, const float* __restrict__ emb,
                             float* __restrict__ h, ushort* __restrict__ hb) {
  const int t = blockIdx.x;       // token 0..32767
  const int i = threadIdx.x;      // pair 0..255
  const int s = t & (SEQ-1);
  const int tok = x[t];
  const float freq = expf(-(float)i * (9.210340371976184f / 256.0f)); // 10000^(-i/256)
  const float th = (float)s * freq;
  const float sn = sinf(th), cs = cosf(th);
  const size_t base = (size_t)t*DMODEL;
  const float v0 = emb[(size_t)tok*DMODEL + 2*i]     + sn;
  const float v1 = emb[(size_t)tok*DMODEL + 2*i + 1] + cs;
  h[base + 2*i]  = v0;  h[base + 2*i + 1]  = v1;
  hb[base + 2*i] = f2h(v0); hb[base + 2*i + 1] = f2h(v1);
}

// ---------------- tiled f16 MFMA GEMM: C = A[M,K] @ Bt[N,K]^T ----------------
// EPI: 0 = bias->f16 rowmajor, 1 = bias+relu->f16, 2 = bias->f32, 3 = QKV scatter

template<int EPI>
__global__ __launch_bounds__(256) void gemm128(
    const ushort* __restrict__ A, const ushort* __restrict__ Bt,
    const float* __restrict__ bias,
    ushort* __restrict__ outb, float* __restrict__ outf,
    ushort* __restrict__ qo, ushort* __restrict__ kTo, ushort* __restrict__ vTo,
    int N, int K, int ldc) {
  __shared__ __align__(16) ushort lA[128*64];
  __shared__ __align__(16) ushort lB[128*64];
  const int tid  = threadIdx.x;
  const int lane = tid & 63;
  const int w    = tid >> 6;
  const int wr   = w >> 1, wc = w & 1;
  const int bm = blockIdx.x, bn = blockIdx.y;

  const int ra = tid >> 3;   // staging row within 32-row group
  const int ca = tid & 7;    // staging 16B-chunk within row
  const size_t arow0 = (size_t)bm * 128;
  const size_t brow0 = (size_t)bn * 128;

  f32x4 acc[4][4] = {};

  const int nK = K >> 6;
  for (int kt = 0; kt < nK; ++kt) {
    const int k0 = kt << 6;
    #pragma unroll
    for (int i = 0; i < 4; ++i) {
      const int r  = i*32 + ra;
      const int cc = ca ^ (r & 7);                 // pre-swizzled global source
      load_lds16(A  + (arow0 + r)*K + k0 + cc*8, (char*)lA + (i*256 + tid)*16);
      load_lds16(Bt + (brow0 + r)*K + k0 + cc*8, (char*)lB + (i*256 + tid)*16);
    }
    __syncthreads();
    #pragma unroll
    for (int kk = 0; kk < 2; ++kk) {
      hfrag af[4], bfr[4];
      #pragma unroll
      for (int m = 0; m < 4; ++m) {
        const int r  = wr*64 + m*16 + (lane & 15);
        const int ck = kk*4 + (lane >> 4);
        af[m] = *(const hfrag*)((const char*)lA + r*128 + ((ck ^ (r & 7)) * 16));
      }
      #pragma unroll
      for (int n = 0; n < 4; ++n) {
        const int r  = wc*64 + n*16 + (lane & 15);
        const int ck = kk*4 + (lane >> 4);
        bfr[n] = *(const hfrag*)((const char*)lB + r*128 + ((ck ^ (r & 7)) * 16));
      }
      #pragma unroll
      for (int m = 0; m < 4; ++m)
        #pragma unroll
        for (int n = 0; n < 4; ++n)
          acc[m][n] = mfma16(af[m], bfr[n], acc[m][n]);
    }
    __syncthreads();
  }

  #pragma unroll
  for (int m = 0; m < 4; ++m) {
    #pragma unroll
    for (int n = 0; n < 4; ++n) {
      #pragma unroll
      for (int r4 = 0; r4 < 4; ++r4) {
        const int row = bm*128 + wr*64 + m*16 + ((lane >> 4) * 4) + r4;
        const int col = bn*128 + wc*64 + n*16 + (lane & 15);
        const float v = acc[m][n][r4] + bias[col];
        if constexpr (EPI == 0) {
          outb[(size_t)row*ldc + col] = f2h(v);
        } else if constexpr (EPI == 1) {
          outb[(size_t)row*ldc + col] = f2h(fmaxf(v, 0.0f));
        } else if constexpr (EPI == 2) {
          outf[(size_t)row*ldc + col] = v;
        } else {
          const int which = col >> 9;
          const int hh = (col >> 6) & 7;
          const int e  = col & 63;
          const int b  = row >> 7, s = row & 127;
          const int bh = b*NHEADS + hh;
          const ushort uv = f2h(v);
          if (which == 0)      qo [((size_t)bh*SEQ + s)*HDIM + e] = uv;     // [b][h][s][e]
          else if (which == 1) kTo[((size_t)bh*HDIM + e)*SEQ + s] = uv;     // [b][h][e][s]
          else                 vTo[((size_t)bh*HDIM + e)*SEQ + s] = uv;     // [b][h][e][s]
        }
      }
    }
  }
}

// ---------------- attention (no softmax): out = q @ (scale * k^T v) ----------------
// one wave per (b,h); 4 (b,h) per block

__global__ __launch_bounds__(256) void attn_kernel(
    const ushort* __restrict__ q, const ushort* __restrict__ kT,
    const ushort* __restrict__ vT, float* __restrict__ outp) {
  __shared__ __align__(16) ushort ktvT[4][64*72];   // padded rows: 144B -> 2-way conflicts only
  const int tid = threadIdx.x;
  const int w = tid >> 6, lane = tid & 63;
  const int bh = blockIdx.x*4 + w;
  const int b = bh >> 3, h = bh & 7;
  const ushort* kTp = kT + (size_t)bh*HDIM*SEQ;
  const ushort* vTp = vT + (size_t)bh*HDIM*SEQ;
  const ushort* qp  = q  + (size_t)bh*SEQ*HDIM;

  // ktv[e1][e2] = sum_s k[s][e1]*v[s][e2]  (A = kT rows e1, B = vT rows e2)
  f32x4 acc1[4][4] = {};
  #pragma unroll
  for (int sb = 0; sb < 4; ++sb) {
    const int sbase = sb*32 + (lane >> 4)*8;
    hfrag ak[4], av[4];
    #pragma unroll
    for (int m = 0; m < 4; ++m) {
      const int e = m*16 + (lane & 15);
      ak[m] = *(const hfrag*)(kTp + (size_t)e*SEQ + sbase);
      av[m] = *(const hfrag*)(vTp + (size_t)e*SEQ + sbase);
    }
    #pragma unroll
    for (int m = 0; m < 4; ++m)
      #pragma unroll
      for (int n = 0; n < 4; ++n)
        acc1[m][n] = mfma16(ak[m], av[n], acc1[m][n]);
  }
  // store scale*ktv transposed: ktvT[e2][e1]
  ushort* lds = &ktvT[w][0];
  #pragma unroll
  for (int m = 0; m < 4; ++m)
    #pragma unroll
    for (int n = 0; n < 4; ++n)
      #pragma unroll
      for (int r4 = 0; r4 < 4; ++r4) {
        const int e1 = m*16 + (lane >> 4)*4 + r4;
        const int e2 = n*16 + (lane & 15);
        lds[e2*72 + e1] = f2h(acc1[m][n][r4] * 0.125f);
      }
  __syncthreads();

  // attn[s][e2] = sum_e1 q[s][e1] * ktv[e1][e2]
  f32x4 acc2[8][4] = {};
  #pragma unroll
  for (int eb = 0; eb < 2; ++eb) {
    const int e1b = eb*32 + (lane >> 4)*8;
    hfrag aq[8], bk2[4];
    #pragma unroll
    for (int m = 0; m < 8; ++m) {
      const int s = m*16 + (lane & 15);
      aq[m] = *(const hfrag*)(qp + (size_t)s*HDIM + e1b);
    }
    #pragma unroll
    for (int n = 0; n < 4; ++n) {
      const int e2 = n*16 + (lane & 15);
      bk2[n] = *(const hfrag*)(lds + e2*72 + e1b);
    }
    #pragma unroll
    for (int m = 0; m < 8; ++m)
      #pragma unroll
      for (int n = 0; n < 4; ++n)
        acc2[m][n] = mfma16(aq[m], bk2[n], acc2[m][n]);
  }
  #pragma unroll
  for (int m = 0; m < 8; ++m)
    #pragma unroll
    for (int n = 0; n < 4; ++n)
      #pragma unroll
      for (int r4 = 0; r4 < 4; ++r4) {
        const int s  = m*16 + (lane >> 4)*4 + r4;
        const int e2 = n*16 + (lane & 15);
        outp[((size_t)b*SEQ + s)*DMODEL + h*HDIM + e2] = acc2[m][n][r4];
      }
}

// ---------------- residual + LayerNorm over (S,D) per batch sample ----------------

__global__ __launch_bounds__(1024) void resid_ln(
    const float* __restrict__ delta, float* __restrict__ h, ushort* __restrict__ hb) {
  const int b = blockIdx.x;
  const size_t base = (size_t)b * (SEQ*DMODEL);
  float r[64];
  float s = 0.f, q = 0.f;
  #pragma unroll
  for (int j = 0; j < 64; ++j) {
    const float v = h[base + j*1024 + threadIdx.x] + delta[base + j*1024 + threadIdx.x];
    r[j] = v; s += v; q += v*v;
  }
  #pragma unroll
  for (int off = 32; off > 0; off >>= 1) {
    s += __shfl_down(s, off);
    q += __shfl_down(q, off);
  }
  __shared__ float ws_[16], wq_[16];
  __shared__ float stat[2];
  const int w = threadIdx.x >> 6, lane = threadIdx.x & 63;
  if (lane == 0) { ws_[w] = s; wq_[w] = q; }
  __syncthreads();
  if (threadIdx.x == 0) {
    float S = 0.f, Q = 0.f;
    #pragma unroll
    for (int i2 = 0; i2 < 16; ++i2) { S += ws_[i2]; Q += wq_[i2]; }
    const float mean = S * (1.0f/65536.0f);
    const float var  = Q * (1.0f/65536.0f) - mean*mean;
    stat[0] = mean; stat[1] = rsqrtf(var + 1e-5f);
  }
  __syncthreads();
  const float mean = stat[0], rstd = stat[1];
  #pragma unroll
  for (int j = 0; j < 64; ++j) {
    const float o = (r[j] - mean) * rstd;
    const size_t idx = base + j*1024 + threadIdx.x;
    h[idx] = o; hb[idx] = f2h(o);
  }
}

// ---------------- driver ----------------

extern "C" void kernel_launch(void* const* d_in, const int* in_sizes, int n_in,
                              void* d_out, int out_size, void* d_ws, size_t ws_size,
                              hipStream_t stream) {
  const int*   x   = (const int*)d_in[0];
  const float* emb = (const float*)d_in[1];
  const float* Wq  = (const float*)d_in[2];
  const float* bq  = (const float*)d_in[3];
  const float* Wk  = (const float*)d_in[4];
  const float* bk  = (const float*)d_in[5];
  const float* Wv  = (const float*)d_in[6];
  const float* bv  = (const float*)d_in[7];
  const float* W1  = (const float*)d_in[8];
  const float* b1  = (const float*)d_in[9];
  const float* W2  = (const float*)d_in[10];
  const float* b2  = (const float*)d_in[11];
  float* h = (float*)d_out;

  char* p = (char*)d_ws;
  size_t off = 0;
  auto alloc = [&](size_t bytes) { char* r = p + off; off += (bytes + 255) & ~(size_t)255; return r; };
  ushort* Wqkv_t = (ushort*)alloc((size_t)NLAYERS*1536*512*2);
  ushort* W1t    = (ushort*)alloc((size_t)NLAYERS*INNER*512*2);
  ushort* W2t    = (ushort*)alloc((size_t)NLAYERS*512*INNER*2);
  float*  biasq  = (float*)alloc((size_t)NLAYERS*1536*4);
  ushort* hbf    = (ushort*)alloc((size_t)NTOK*512*2);
  ushort* qb     = (ushort*)alloc((size_t)NTOK*512*2);   // also reused as ff1 chunk buffer
  ushort* kTb    = (ushort*)alloc((size_t)NTOK*512*2);
  ushort* vTb    = (ushort*)alloc((size_t)NTOK*512*2);
  float*  attnb  = (float*)alloc((size_t)NTOK*512*4);    // also reused as ff2 output

  prep_qkv<<<(NLAYERS*1536*512 + 255)/256, 256, 0, stream>>>(Wq, Wk, Wv, bq, bk, bv, Wqkv_t, biasq);
  prep_w1<<<(NLAYERS*INNER*512 + 255)/256, 256, 0, stream>>>(W1, W1t);
  prep_w2<<<(NLAYERS*512*INNER + 255)/256, 256, 0, stream>>>(W2, W2t);
  embed_kernel<<<NTOK, 256, 0, stream>>>(x, emb, h, hbf);

  for (int l = 0; l < NLAYERS; ++l) {
    gemm128<3><<<dim3(NTOK/128, 12), 256, 0, stream>>>(
        hbf, Wqkv_t + (size_t)l*1536*512, biasq + (size_t)l*1536,
        nullptr, nullptr, qb, kTb, vTb, 1536, 512, 0);
    attn_kernel<<<BATCH*NHEADS/4, 256, 0, stream>>>(qb, kTb, vTb, attnb);
    resid_ln<<<BATCH, 1024, 0, stream>>>(attnb, h, hbf);
    for (int c = 0; c < 4; ++c) {
      gemm128<1><<<dim3(64, INNER/128), 256, 0, stream>>>(
          hbf + (size_t)c*8192*512, W1t + (size_t)l*INNER*512, b1 + (size_t)l*INNER,
          qb, nullptr, nullptr, nullptr, nullptr, INNER, 512, INNER);
      gemm128<2><<<dim3(64, 512/128), 256, 0, stream>>>(
          qb, W2t + (size_t)l*512*INNER, b2 + (size_t)l*512,
          nullptr, attnb + (size_t)c*8192*512, nullptr, nullptr, nullptr, 512, INNER, 512);
    }
    resid_ln<<<BATCH, 1024, 0, stream>>>(attnb, h, hbf);
  }
}

// Round 3
// 3080.968 us; speedup vs baseline: 1.0549x; 1.0549x over previous
//
#include <hip/hip_runtime.h>
#include <stdint.h>

#define NLAYERS 6
#define DMODEL  512
#define NHEADS  8
#define HDIM    64
#define INNER   2048
#define SEQ     128
#define BATCH   256
#define NTOK    (BATCH*SEQ)

typedef __attribute__((ext_vector_type(4))) float f32x4;
typedef __attribute__((ext_vector_type(8))) _Float16 hfrag;

typedef const __attribute__((address_space(1))) void* gas1p;
typedef __attribute__((address_space(3))) void* las3p;

__device__ __forceinline__ void load_lds16(const void* g, void* l) {
  __builtin_amdgcn_global_load_lds((gas1p)(uintptr_t)g, (las3p)(uint32_t)(uintptr_t)l, 16, 0, 0);
}

__device__ __forceinline__ ushort f2h(float f) {
  return __builtin_bit_cast(ushort, (_Float16)f);
}
__device__ __forceinline__ float h2f(ushort u) {
  return (float)__builtin_bit_cast(_Float16, u);
}

__device__ __forceinline__ f32x4 mfma16(hfrag a, hfrag b, f32x4 c) {
  return __builtin_amdgcn_mfma_f32_16x16x32_f16(a, b, c, 0, 0, 0);
}

// ---------------- weight prep (f32 -> f16, transposed to [N][K]) ----------------

__global__ void prep_qkv(const float* __restrict__ Wq, const float* __restrict__ Wk,
                         const float* __restrict__ Wv, const float* __restrict__ bq,
                         const float* __restrict__ bk, const float* __restrict__ bv,
                         ushort* __restrict__ Wt, float* __restrict__ biasq) {
  int idx = blockIdx.x*256 + threadIdx.x;
  if (idx >= NLAYERS*1536*512) return;
  const int k = idx & 511;
  const int n = (idx >> 9) % 1536;
  const int l = idx / (1536*512);
  const int which = n >> 9, hh = (n >> 6) & 7, e = n & 63;
  const float* W = (which == 0) ? Wq : ((which == 1) ? Wk : Wv);
  Wt[idx] = f2h(W[(((size_t)l*NHEADS + hh)*DMODEL + k)*HDIM + e]);
  if (k == 0) {
    const float* bb = (which == 0) ? bq : ((which == 1) ? bk : bv);
    biasq[l*1536 + n] = bb[((size_t)l*NHEADS + hh)*HDIM + e];
  }
}

__global__ void prep_w1(const float* __restrict__ W1, ushort* __restrict__ W1t) {
  int idx = blockIdx.x*256 + threadIdx.x;
  if (idx >= NLAYERS*INNER*512) return;
  const int k = idx & 511;
  const int n = (idx >> 9) % INNER;
  const int l = idx / (INNER*512);
  W1t[idx] = f2h(W1[((size_t)l*DMODEL + k)*INNER + n]);
}

__global__ void prep_w2(const float* __restrict__ W2, ushort* __restrict__ W2t) {
  int idx = blockIdx.x*256 + threadIdx.x;
  if (idx >= NLAYERS*512*INNER) return;
  const int k = idx & 2047;
  const int n = (idx >> 11) & 511;
  const int l = idx / (512*INNER);
  W2t[idx] = f2h(W2[((size_t)l*INNER + k)*DMODEL + n]);
}

// ---------------- embedding + positional encoding ----------------

__global__ void embed_kernel(const int* __restrict__ x, const float* __restrict__ emb,
                             float* __restrict__ h, ushort* __restrict__ hb) {
  const int t = blockIdx.x;       // token 0..32767
  const int i = threadIdx.x;      // pair 0..255
  const int s = t & (SEQ-1);
  const int tok = x[t];
  const float freq = expf(-(float)i * (9.210340371976184f / 256.0f)); // 10000^(-i/256)
  const float th = (float)s * freq;
  const float sn = sinf(th), cs = cosf(th);
  const size_t base = (size_t)t*DMODEL;
  const float v0 = emb[(size_t)tok*DMODEL + 2*i]     + sn;
  const float v1 = emb[(size_t)tok*DMODEL + 2*i + 1] + cs;
  h[base + 2*i]  = v0;  h[base + 2*i + 1]  = v1;
  hb[base + 2*i] = f2h(v0); hb[base + 2*i + 1] = f2h(v1);
}

// ---------------- tiled f16 MFMA GEMM: C = A[M,K] @ Bt[N,K]^T ----------------
// grid = (Ntiles, Mtiles): consecutive blocks share the A panel (L2 reuse).
// EPI: 0 = bias->f16, 1 = bias+relu->f16

template<int EPI>
__global__ __launch_bounds__(256) void gemm128(
    const ushort* __restrict__ A, const ushort* __restrict__ Bt,
    const float* __restrict__ bias, ushort* __restrict__ outb,
    int K, int ldc) {
  __shared__ __align__(16) ushort lA[128*64];
  __shared__ __align__(16) ushort lB[128*64];
  const int tid  = threadIdx.x;
  const int lane = tid & 63;
  const int w    = tid >> 6;
  const int wr   = w >> 1, wc = w & 1;
  const int bn = blockIdx.x, bm = blockIdx.y;

  const int ra = tid >> 3;   // staging row within 32-row group
  const int ca = tid & 7;    // staging 16B-chunk within row
  const size_t arow0 = (size_t)bm * 128;
  const size_t brow0 = (size_t)bn * 128;

  f32x4 acc[4][4] = {};

  const int nK = K >> 6;
  for (int kt = 0; kt < nK; ++kt) {
    const int k0 = kt << 6;
    #pragma unroll
    for (int i = 0; i < 4; ++i) {
      const int r  = i*32 + ra;
      const int cc = ca ^ (r & 7);                 // pre-swizzled global source
      load_lds16(A  + (arow0 + r)*K + k0 + cc*8, (char*)lA + (i*256 + tid)*16);
      load_lds16(Bt + (brow0 + r)*K + k0 + cc*8, (char*)lB + (i*256 + tid)*16);
    }
    __syncthreads();
    #pragma unroll
    for (int kk = 0; kk < 2; ++kk) {
      hfrag af[4], bfr[4];
      #pragma unroll
      for (int m = 0; m < 4; ++m) {
        const int r  = wr*64 + m*16 + (lane & 15);
        const int ck = kk*4 + (lane >> 4);
        af[m] = *(const hfrag*)((const char*)lA + r*128 + ((ck ^ (r & 7)) * 16));
      }
      #pragma unroll
      for (int n = 0; n < 4; ++n) {
        const int r  = wc*64 + n*16 + (lane & 15);
        const int ck = kk*4 + (lane >> 4);
        bfr[n] = *(const hfrag*)((const char*)lB + r*128 + ((ck ^ (r & 7)) * 16));
      }
      #pragma unroll
      for (int m = 0; m < 4; ++m)
        #pragma unroll
        for (int n = 0; n < 4; ++n)
          acc[m][n] = mfma16(af[m], bfr[n], acc[m][n]);
    }
    __syncthreads();
  }

  #pragma unroll
  for (int m = 0; m < 4; ++m) {
    #pragma unroll
    for (int n = 0; n < 4; ++n) {
      #pragma unroll
      for (int r4 = 0; r4 < 4; ++r4) {
        const int row = bm*128 + wr*64 + m*16 + ((lane >> 4) * 4) + r4;
        const int col = bn*128 + wc*64 + n*16 + (lane & 15);
        const float v = acc[m][n][r4] + bias[col];
        if constexpr (EPI == 0) {
          outb[(size_t)row*ldc + col] = f2h(v);
        } else {
          outb[(size_t)row*ldc + col] = f2h(fmaxf(v, 0.0f));
        }
      }
    }
  }
}

// ---------------- attention (no softmax): out = q @ (scale * k^T v) ----------------
// qkv dense layout [token][1536] (q | k | v, each [h][e]).
// one wave per (b,h); 4 per block; per-wave LDS transpose of k,v chunks.

__global__ __launch_bounds__(256) void attn_kernel(
    const ushort* __restrict__ qkv, ushort* __restrict__ outb) {
  __shared__ __align__(16) ushort wbuf[4][8192];   // 16KB per wave
  const int tid = threadIdx.x;
  const int w = tid >> 6, lane = tid & 63;
  const int bh = blockIdx.x*4 + w;
  const int b = bh >> 3, h = bh & 7;
  const ushort* tokbase = qkv + (size_t)b*SEQ*1536;
  ushort* lds = &wbuf[w][0];
  ushort* kch = lds;            // swizzled [32][64]
  ushort* vch = lds + 2048;

  // ktv[e1][e2] = sum_s k[s][e1] * v[s][e2]
  f32x4 acc1[4][4] = {};
  #pragma unroll 1
  for (int sb = 0; sb < 4; ++sb) {
    const int s0 = sb*32;
    const int sr = lane >> 1;
    #pragma unroll
    for (int i = 0; i < 4; ++i) {
      const int cc  = i*2 + (lane & 1);
      const int ccs = cc ^ (sr & 7);               // bank-spread swizzle (16B units)
      const ushort* g = tokbase + (size_t)(s0+sr)*1536 + h*64 + cc*8;
      *(uint4*)(kch + sr*64 + ccs*8) = *(const uint4*)(g + 512);
      *(uint4*)(vch + sr*64 + ccs*8) = *(const uint4*)(g + 1024);
    }
    hfrag ak[4], av[4];
    #pragma unroll
    for (int m = 0; m < 4; ++m) {
      const int e1 = m*16 + (lane & 15);
      const int ccb = e1 >> 3, el = e1 & 7;
      #pragma unroll
      for (int j = 0; j < 8; ++j) {
        const int s = (lane >> 4)*8 + j;
        ak[m][j] = __builtin_bit_cast(_Float16, kch[s*64 + ((ccb ^ (s & 7))*8) + el]);
        av[m][j] = __builtin_bit_cast(_Float16, vch[s*64 + ((ccb ^ (s & 7))*8) + el]);
      }
    }
    #pragma unroll
    for (int m = 0; m < 4; ++m)
      #pragma unroll
      for (int n = 0; n < 4; ++n)
        acc1[m][n] = mfma16(ak[m], av[n], acc1[m][n]);
  }

  // store scale*ktv transposed into per-wave LDS: tv[e2][e1], padded rows (72)
  ushort* tv = lds;
  #pragma unroll
  for (int m = 0; m < 4; ++m)
    #pragma unroll
    for (int n = 0; n < 4; ++n)
      #pragma unroll
      for (int r4 = 0; r4 < 4; ++r4) {
        const int e1 = m*16 + (lane >> 4)*4 + r4;
        const int e2 = n*16 + (lane & 15);
        tv[e2*72 + e1] = f2h(acc1[m][n][r4] * 0.125f);
      }

  // attn[s][e2] = sum_e1 q[s][e1] * ktv[e1][e2]
  f32x4 acc2[8][4] = {};
  #pragma unroll
  for (int eb = 0; eb < 2; ++eb) {
    const int e1b = eb*32 + (lane >> 4)*8;
    hfrag aq[8], bk2[4];
    #pragma unroll
    for (int m = 0; m < 8; ++m) {
      const int s = m*16 + (lane & 15);
      aq[m] = *(const hfrag*)(tokbase + (size_t)s*1536 + h*64 + e1b);
    }
    #pragma unroll
    for (int n = 0; n < 4; ++n) {
      const int e2 = n*16 + (lane & 15);
      bk2[n] = *(const hfrag*)(tv + e2*72 + e1b);
    }
    #pragma unroll
    for (int m = 0; m < 8; ++m)
      #pragma unroll
      for (int n = 0; n < 4; ++n)
        acc2[m][n] = mfma16(aq[m], bk2[n], acc2[m][n]);
  }
  #pragma unroll
  for (int m = 0; m < 8; ++m)
    #pragma unroll
    for (int n = 0; n < 4; ++n)
      #pragma unroll
      for (int r4 = 0; r4 < 4; ++r4) {
        const int s  = m*16 + (lane >> 4)*4 + r4;
        const int e2 = n*16 + (lane & 15);
        outb[((size_t)b*SEQ + s)*DMODEL + h*HDIM + e2] = f2h(acc2[m][n][r4]);
      }
}

// ---------------- residual + LayerNorm over (S,D) per batch sample ----------------
// delta is f16; h stays f32 (also the final output); hb is the f16 mirror.

__global__ __launch_bounds__(1024) void resid_ln(
    const ushort* __restrict__ delta, float* __restrict__ h, ushort* __restrict__ hb) {
  const int b = blockIdx.x;
  const size_t base = (size_t)b * (SEQ*DMODEL);
  float2 r[32];
  float s = 0.f, q = 0.f;
  #pragma unroll
  for (int j = 0; j < 32; ++j) {
    const size_t idx = base + j*2048 + threadIdx.x*2;
    const float2 hv = *(const float2*)(h + idx);
    const uint dv = *(const uint*)(delta + idx);
    const float v0 = hv.x + h2f((ushort)(dv & 0xffffu));
    const float v1 = hv.y + h2f((ushort)(dv >> 16));
    r[j].x = v0; r[j].y = v1;
    s += v0 + v1; q += v0*v0 + v1*v1;
  }
  #pragma unroll
  for (int off = 32; off > 0; off >>= 1) {
    s += __shfl_down(s, off);
    q += __shfl_down(q, off);
  }
  __shared__ float ws_[16], wq_[16];
  __shared__ float stat[2];
  const int w = threadIdx.x >> 6, lane = threadIdx.x & 63;
  if (lane == 0) { ws_[w] = s; wq_[w] = q; }
  __syncthreads();
  if (threadIdx.x == 0) {
    float S = 0.f, Q = 0.f;
    #pragma unroll
    for (int i2 = 0; i2 < 16; ++i2) { S += ws_[i2]; Q += wq_[i2]; }
    const float mean = S * (1.0f/65536.0f);
    const float var  = Q * (1.0f/65536.0f) - mean*mean;
    stat[0] = mean; stat[1] = rsqrtf(var + 1e-5f);
  }
  __syncthreads();
  const float mean = stat[0], rstd = stat[1];
  #pragma unroll
  for (int j = 0; j < 32; ++j) {
    const size_t idx = base + j*2048 + threadIdx.x*2;
    const float o0 = (r[j].x - mean) * rstd;
    const float o1 = (r[j].y - mean) * rstd;
    *(float2*)(h + idx) = make_float2(o0, o1);
    *(uint*)(hb + idx) = (uint)f2h(o0) | ((uint)f2h(o1) << 16);
  }
}

// ---------------- driver ----------------

extern "C" void kernel_launch(void* const* d_in, const int* in_sizes, int n_in,
                              void* d_out, int out_size, void* d_ws, size_t ws_size,
                              hipStream_t stream) {
  const int*   x   = (const int*)d_in[0];
  const float* emb = (const float*)d_in[1];
  const float* Wq  = (const float*)d_in[2];
  const float* bq  = (const float*)d_in[3];
  const float* Wk  = (const float*)d_in[4];
  const float* bk  = (const float*)d_in[5];
  const float* Wv  = (const float*)d_in[6];
  const float* bv  = (const float*)d_in[7];
  const float* W1  = (const float*)d_in[8];
  const float* b1  = (const float*)d_in[9];
  const float* W2  = (const float*)d_in[10];
  const float* b2  = (const float*)d_in[11];
  float* h = (float*)d_out;

  char* p = (char*)d_ws;
  size_t off = 0;
  auto alloc = [&](size_t bytes) { char* r = p + off; off += (bytes + 255) & ~(size_t)255; return r; };
  ushort* Wqkv_t = (ushort*)alloc((size_t)NLAYERS*1536*512*2);
  ushort* W1t    = (ushort*)alloc((size_t)NLAYERS*INNER*512*2);
  ushort* W2t    = (ushort*)alloc((size_t)NLAYERS*512*INNER*2);
  float*  biasq  = (float*)alloc((size_t)NLAYERS*1536*4);
  ushort* hbf    = (ushort*)alloc((size_t)NTOK*512*2);
  ushort* big    = (ushort*)alloc((size_t)NTOK*1536*2);  // qkv buffer; reused as FF inner buffer
  ushort* attnb  = (ushort*)alloc((size_t)NTOK*512*2);   // attn-out / ff2-out (f16 delta)

  prep_qkv<<<(NLAYERS*1536*512 + 255)/256, 256, 0, stream>>>(Wq, Wk, Wv, bq, bk, bv, Wqkv_t, biasq);
  prep_w1<<<(NLAYERS*INNER*512 + 255)/256, 256, 0, stream>>>(W1, W1t);
  prep_w2<<<(NLAYERS*512*INNER + 255)/256, 256, 0, stream>>>(W2, W2t);
  embed_kernel<<<NTOK, 256, 0, stream>>>(x, emb, h, hbf);

  for (int l = 0; l < NLAYERS; ++l) {
    // QKV: [32768,512] x [1536,512]^T -> dense [32768,1536] f16
    gemm128<0><<<dim3(12, NTOK/128), 256, 0, stream>>>(
        hbf, Wqkv_t + (size_t)l*1536*512, biasq + (size_t)l*1536, big, 512, 1536);
    attn_kernel<<<BATCH*NHEADS/4, 256, 0, stream>>>(big, attnb);
    resid_ln<<<BATCH, 1024, 0, stream>>>(attnb, h, hbf);
    // FF in two half-M chunks (16384 rows), inner buffer reuses `big`
    for (int c = 0; c < 2; ++c) {
      gemm128<1><<<dim3(16, 128), 256, 0, stream>>>(
          hbf + (size_t)c*16384*512, W1t + (size_t)l*INNER*512, b1 + (size_t)l*INNER,
          big, 512, INNER);
      gemm128<0><<<dim3(4, 128), 256, 0, stream>>>(
          big, W2t + (size_t)l*512*INNER, b2 + (size_t)l*512,
          attnb + (size_t)c*16384*512, INNER, 512);
    }
    resid_ln<<<BATCH, 1024, 0, stream>>>(attnb, h, hbf);
  }
}

// Round 4
// 2121.377 us; speedup vs baseline: 1.5321x; 1.4523x over previous
//
#include <hip/hip_runtime.h>
#include <stdint.h>

#define NLAYERS 6
#define DMODEL  512
#define NHEADS  8
#define HDIM    64
#define INNER   2048
#define SEQ     128
#define BATCH   256
#define NTOK    (BATCH*SEQ)

typedef __attribute__((ext_vector_type(4))) float f32x4;
typedef __attribute__((ext_vector_type(8))) _Float16 hfrag;

typedef const __attribute__((address_space(1))) void* gas1p;
typedef __attribute__((address_space(3))) void* las3p;

__device__ __forceinline__ void load_lds16(const void* g, void* l) {
  __builtin_amdgcn_global_load_lds((gas1p)(uintptr_t)g, (las3p)(uint32_t)(uintptr_t)l, 16, 0, 0);
}

__device__ __forceinline__ ushort f2h(float f) {
  return __builtin_bit_cast(ushort, (_Float16)f);
}
__device__ __forceinline__ float h2f(ushort u) {
  return (float)__builtin_bit_cast(_Float16, u);
}

__device__ __forceinline__ f32x4 mfma16(hfrag a, hfrag b, f32x4 c) {
  return __builtin_amdgcn_mfma_f32_16x16x32_f16(a, b, c, 0, 0, 0);
}

// ---------------- weight prep (f32 -> f16, transposed to [N][K]) ----------------

__global__ void prep_qkv(const float* __restrict__ Wq, const float* __restrict__ Wk,
                         const float* __restrict__ Wv, const float* __restrict__ bq,
                         const float* __restrict__ bk, const float* __restrict__ bv,
                         ushort* __restrict__ Wt, float* __restrict__ biasq) {
  int idx = blockIdx.x*256 + threadIdx.x;
  if (idx >= NLAYERS*1536*512) return;
  const int k = idx & 511;
  const int n = (idx >> 9) % 1536;
  const int l = idx / (1536*512);
  const int which = n >> 9, hh = (n >> 6) & 7, e = n & 63;
  const float* W = (which == 0) ? Wq : ((which == 1) ? Wk : Wv);
  Wt[idx] = f2h(W[(((size_t)l*NHEADS + hh)*DMODEL + k)*HDIM + e]);
  if (k == 0) {
    const float* bb = (which == 0) ? bq : ((which == 1) ? bk : bv);
    biasq[l*1536 + n] = bb[((size_t)l*NHEADS + hh)*HDIM + e];
  }
}

__global__ void prep_w1(const float* __restrict__ W1, ushort* __restrict__ W1t) {
  int idx = blockIdx.x*256 + threadIdx.x;
  if (idx >= NLAYERS*INNER*512) return;
  const int k = idx & 511;
  const int n = (idx >> 9) % INNER;
  const int l = idx / (INNER*512);
  W1t[idx] = f2h(W1[((size_t)l*DMODEL + k)*INNER + n]);
}

__global__ void prep_w2(const float* __restrict__ W2, ushort* __restrict__ W2t) {
  int idx = blockIdx.x*256 + threadIdx.x;
  if (idx >= NLAYERS*512*INNER) return;
  const int k = idx & 2047;
  const int n = (idx >> 11) & 511;
  const int l = idx / (512*INNER);
  W2t[idx] = f2h(W2[((size_t)l*INNER + k)*DMODEL + n]);
}

// ---------------- embedding + positional encoding (f16 residual stream) ----------------

__global__ void embed_kernel(const int* __restrict__ x, const float* __restrict__ emb,
                             ushort* __restrict__ hb) {
  const int t = blockIdx.x;       // token 0..32767
  const int i = threadIdx.x;      // pair 0..255
  const int s = t & (SEQ-1);
  const int tok = x[t];
  const float freq = expf(-(float)i * (9.210340371976184f / 256.0f)); // 10000^(-i/256)
  const float th = (float)s * freq;
  const float sn = sinf(th), cs = cosf(th);
  const size_t base = (size_t)t*DMODEL;
  const float v0 = emb[(size_t)tok*DMODEL + 2*i]     + sn;
  const float v1 = emb[(size_t)tok*DMODEL + 2*i + 1] + cs;
  *(uint*)(hb + base + 2*i) = (uint)f2h(v0) | ((uint)f2h(v1) << 16);
}

// ---------------- tiled f16 MFMA GEMM: C = A[M,K] @ Bt[N,K]^T ----------------
// grid = (Ntiles, Mtiles): consecutive blocks share the A panel (L2 reuse).
// EPI: 0 = bias->f16, 1 = bias+relu->f16

template<int EPI>
__global__ __launch_bounds__(256) void gemm128(
    const ushort* __restrict__ A, const ushort* __restrict__ Bt,
    const float* __restrict__ bias, ushort* __restrict__ outb,
    int K, int ldc) {
  __shared__ __align__(16) ushort lA[128*64];
  __shared__ __align__(16) ushort lB[128*64];
  const int tid  = threadIdx.x;
  const int lane = tid & 63;
  const int w    = tid >> 6;
  const int wr   = w >> 1, wc = w & 1;
  const int bn = blockIdx.x, bm = blockIdx.y;

  const int ra = tid >> 3;   // staging row within 32-row group
  const int ca = tid & 7;    // staging 16B-chunk within row
  const size_t arow0 = (size_t)bm * 128;
  const size_t brow0 = (size_t)bn * 128;

  f32x4 acc[4][4] = {};

  const int nK = K >> 6;
  for (int kt = 0; kt < nK; ++kt) {
    const int k0 = kt << 6;
    #pragma unroll
    for (int i = 0; i < 4; ++i) {
      const int r  = i*32 + ra;
      const int cc = ca ^ (r & 7);                 // pre-swizzled global source
      load_lds16(A  + (arow0 + r)*K + k0 + cc*8, (char*)lA + (i*256 + tid)*16);
      load_lds16(Bt + (brow0 + r)*K + k0 + cc*8, (char*)lB + (i*256 + tid)*16);
    }
    __syncthreads();
    #pragma unroll
    for (int kk = 0; kk < 2; ++kk) {
      hfrag af[4], bfr[4];
      #pragma unroll
      for (int m = 0; m < 4; ++m) {
        const int r  = wr*64 + m*16 + (lane & 15);
        const int ck = kk*4 + (lane >> 4);
        af[m] = *(const hfrag*)((const char*)lA + r*128 + ((ck ^ (r & 7)) * 16));
      }
      #pragma unroll
      for (int n = 0; n < 4; ++n) {
        const int r  = wc*64 + n*16 + (lane & 15);
        const int ck = kk*4 + (lane >> 4);
        bfr[n] = *(const hfrag*)((const char*)lB + r*128 + ((ck ^ (r & 7)) * 16));
      }
      #pragma unroll
      for (int m = 0; m < 4; ++m)
        #pragma unroll
        for (int n = 0; n < 4; ++n)
          acc[m][n] = mfma16(af[m], bfr[n], acc[m][n]);
    }
    __syncthreads();
  }

  #pragma unroll
  for (int m = 0; m < 4; ++m) {
    #pragma unroll
    for (int n = 0; n < 4; ++n) {
      #pragma unroll
      for (int r4 = 0; r4 < 4; ++r4) {
        const int row = bm*128 + wr*64 + m*16 + ((lane >> 4) * 4) + r4;
        const int col = bn*128 + wc*64 + n*16 + (lane & 15);
        const float v = acc[m][n][r4] + bias[col];
        if constexpr (EPI == 0) {
          outb[(size_t)row*ldc + col] = f2h(v);
        } else {
          outb[(size_t)row*ldc + col] = f2h(fmaxf(v, 0.0f));
        }
      }
    }
  }
}

// ---------------- attention (no softmax): out = q @ (scale * k^T v) ----------------
// qkv dense layout [token][1536] (q | k | v, each [h][e]).
// one wave per (b,h); 4 per block; per-wave LDS transpose of k,v chunks.

__global__ __launch_bounds__(256) void attn_kernel(
    const ushort* __restrict__ qkv, ushort* __restrict__ outb) {
  __shared__ __align__(16) ushort wbuf[4][8192];   // 16KB per wave
  const int tid = threadIdx.x;
  const int w = tid >> 6, lane = tid & 63;
  const int bh = blockIdx.x*4 + w;
  const int b = bh >> 3, h = bh & 7;
  const ushort* tokbase = qkv + (size_t)b*SEQ*1536;
  ushort* lds = &wbuf[w][0];
  ushort* kch = lds;            // swizzled [32][64]
  ushort* vch = lds + 2048;

  // ktv[e1][e2] = sum_s k[s][e1] * v[s][e2]
  f32x4 acc1[4][4] = {};
  #pragma unroll 1
  for (int sb = 0; sb < 4; ++sb) {
    const int s0 = sb*32;
    const int sr = lane >> 1;
    #pragma unroll
    for (int i = 0; i < 4; ++i) {
      const int cc  = i*2 + (lane & 1);
      const int ccs = cc ^ (sr & 7);               // bank-spread swizzle (16B units)
      const ushort* g = tokbase + (size_t)(s0+sr)*1536 + h*64 + cc*8;
      *(uint4*)(kch + sr*64 + ccs*8) = *(const uint4*)(g + 512);
      *(uint4*)(vch + sr*64 + ccs*8) = *(const uint4*)(g + 1024);
    }
    hfrag ak[4], av[4];
    #pragma unroll
    for (int m = 0; m < 4; ++m) {
      const int e1 = m*16 + (lane & 15);
      const int ccb = e1 >> 3, el = e1 & 7;
      #pragma unroll
      for (int j = 0; j < 8; ++j) {
        const int s = (lane >> 4)*8 + j;
        ak[m][j] = __builtin_bit_cast(_Float16, kch[s*64 + ((ccb ^ (s & 7))*8) + el]);
        av[m][j] = __builtin_bit_cast(_Float16, vch[s*64 + ((ccb ^ (s & 7))*8) + el]);
      }
    }
    #pragma unroll
    for (int m = 0; m < 4; ++m)
      #pragma unroll
      for (int n = 0; n < 4; ++n)
        acc1[m][n] = mfma16(ak[m], av[n], acc1[m][n]);
  }

  // store scale*ktv transposed into per-wave LDS: tv[e2][e1], padded rows (72)
  ushort* tv = lds;
  #pragma unroll
  for (int m = 0; m < 4; ++m)
    #pragma unroll
    for (int n = 0; n < 4; ++n)
      #pragma unroll
      for (int r4 = 0; r4 < 4; ++r4) {
        const int e1 = m*16 + (lane >> 4)*4 + r4;
        const int e2 = n*16 + (lane & 15);
        tv[e2*72 + e1] = f2h(acc1[m][n][r4] * 0.125f);
      }

  // attn[s][e2] = sum_e1 q[s][e1] * ktv[e1][e2]
  f32x4 acc2[8][4] = {};
  #pragma unroll
  for (int eb = 0; eb < 2; ++eb) {
    const int e1b = eb*32 + (lane >> 4)*8;
    hfrag aq[8], bk2[4];
    #pragma unroll
    for (int m = 0; m < 8; ++m) {
      const int s = m*16 + (lane & 15);
      aq[m] = *(const hfrag*)(tokbase + (size_t)s*1536 + h*64 + e1b);
    }
    #pragma unroll
    for (int n = 0; n < 4; ++n) {
      const int e2 = n*16 + (lane & 15);
      bk2[n] = *(const hfrag*)(tv + e2*72 + e1b);
    }
    #pragma unroll
    for (int m = 0; m < 8; ++m)
      #pragma unroll
      for (int n = 0; n < 4; ++n)
        acc2[m][n] = mfma16(aq[m], bk2[n], acc2[m][n]);
  }
  #pragma unroll
  for (int m = 0; m < 8; ++m)
    #pragma unroll
    for (int n = 0; n < 4; ++n)
      #pragma unroll
      for (int r4 = 0; r4 < 4; ++r4) {
        const int s  = m*16 + (lane >> 4)*4 + r4;
        const int e2 = n*16 + (lane & 15);
        outb[((size_t)b*SEQ + s)*DMODEL + h*HDIM + e2] = f2h(acc2[m][n][r4]);
      }
}

// ---------------- residual + LayerNorm over (S,D) per batch sample ----------------
// f16 residual stream: hb = LN(hb + delta). Cache kept as PACKED f16 (32 VGPRs).
// FINAL: also write f32 to hf (the harness output).

template<bool FINAL>
__global__ __launch_bounds__(1024) void resid_ln(
    const ushort* __restrict__ delta, ushort* __restrict__ hb, float* __restrict__ hf) {
  const int b = blockIdx.x;
  const size_t base = (size_t)b * (SEQ*DMODEL);
  uint4 cache[8];                       // 64 halves packed
  float s = 0.f, q = 0.f;
  #pragma unroll
  for (int j = 0; j < 8; ++j) {
    const size_t idx = base + (size_t)j*8192 + threadIdx.x*8;
    const uint4 hv = *(const uint4*)(hb + idx);
    const uint4 dv = *(const uint4*)(delta + idx);
    uint4 cv;
    #pragma unroll
    for (int c = 0; c < 4; ++c) {
      const uint hu = (&hv.x)[c], du = (&dv.x)[c];
      const float v0 = h2f((ushort)(hu & 0xffffu)) + h2f((ushort)(du & 0xffffu));
      const float v1 = h2f((ushort)(hu >> 16))     + h2f((ushort)(du >> 16));
      s += v0 + v1; q += v0*v0 + v1*v1;
      (&cv.x)[c] = (uint)f2h(v0) | ((uint)f2h(v1) << 16);
    }
    cache[j] = cv;
  }
  #pragma unroll
  for (int off = 32; off > 0; off >>= 1) {
    s += __shfl_down(s, off);
    q += __shfl_down(q, off);
  }
  __shared__ float ws_[16], wq_[16];
  __shared__ float stat[2];
  const int w = threadIdx.x >> 6, lane = threadIdx.x & 63;
  if (lane == 0) { ws_[w] = s; wq_[w] = q; }
  __syncthreads();
  if (threadIdx.x == 0) {
    float S = 0.f, Q = 0.f;
    #pragma unroll
    for (int i2 = 0; i2 < 16; ++i2) { S += ws_[i2]; Q += wq_[i2]; }
    const float mean = S * (1.0f/65536.0f);
    const float var  = Q * (1.0f/65536.0f) - mean*mean;
    stat[0] = mean; stat[1] = rsqrtf(var + 1e-5f);
  }
  __syncthreads();
  const float mean = stat[0], rstd = stat[1];
  #pragma unroll
  for (int j = 0; j < 8; ++j) {
    const size_t idx = base + (size_t)j*8192 + threadIdx.x*8;
    const uint4 cv = cache[j];
    if constexpr (FINAL) {
      #pragma unroll
      for (int c = 0; c < 4; ++c) {
        const uint u = (&cv.x)[c];
        const float o0 = (h2f((ushort)(u & 0xffffu)) - mean) * rstd;
        const float o1 = (h2f((ushort)(u >> 16))     - mean) * rstd;
        *(float2*)(hf + idx + c*2) = make_float2(o0, o1);
      }
    } else {
      uint4 ov;
      #pragma unroll
      for (int c = 0; c < 4; ++c) {
        const uint u = (&cv.x)[c];
        const float o0 = (h2f((ushort)(u & 0xffffu)) - mean) * rstd;
        const float o1 = (h2f((ushort)(u >> 16))     - mean) * rstd;
        (&ov.x)[c] = (uint)f2h(o0) | ((uint)f2h(o1) << 16);
      }
      *(uint4*)(hb + idx) = ov;
    }
  }
}

// ---------------- driver ----------------

extern "C" void kernel_launch(void* const* d_in, const int* in_sizes, int n_in,
                              void* d_out, int out_size, void* d_ws, size_t ws_size,
                              hipStream_t stream) {
  const int*   x   = (const int*)d_in[0];
  const float* emb = (const float*)d_in[1];
  const float* Wq  = (const float*)d_in[2];
  const float* bq  = (const float*)d_in[3];
  const float* Wk  = (const float*)d_in[4];
  const float* bk  = (const float*)d_in[5];
  const float* Wv  = (const float*)d_in[6];
  const float* bv  = (const float*)d_in[7];
  const float* W1  = (const float*)d_in[8];
  const float* b1  = (const float*)d_in[9];
  const float* W2  = (const float*)d_in[10];
  const float* b2  = (const float*)d_in[11];
  float* h = (float*)d_out;

  char* p = (char*)d_ws;
  size_t off = 0;
  auto alloc = [&](size_t bytes) { char* r = p + off; off += (bytes + 255) & ~(size_t)255; return r; };
  ushort* Wqkv_t = (ushort*)alloc((size_t)NLAYERS*1536*512*2);
  ushort* W1t    = (ushort*)alloc((size_t)NLAYERS*INNER*512*2);
  ushort* W2t    = (ushort*)alloc((size_t)NLAYERS*512*INNER*2);
  float*  biasq  = (float*)alloc((size_t)NLAYERS*1536*4);
  ushort* hbf    = (ushort*)alloc((size_t)NTOK*512*2);
  ushort* big    = (ushort*)alloc((size_t)NTOK*1536*2);  // qkv buffer; reused as FF inner buffer
  ushort* attnb  = (ushort*)alloc((size_t)NTOK*512*2);   // attn-out / ff2-out (f16 delta)

  prep_qkv<<<(NLAYERS*1536*512 + 255)/256, 256, 0, stream>>>(Wq, Wk, Wv, bq, bk, bv, Wqkv_t, biasq);
  prep_w1<<<(NLAYERS*INNER*512 + 255)/256, 256, 0, stream>>>(W1, W1t);
  prep_w2<<<(NLAYERS*512*INNER + 255)/256, 256, 0, stream>>>(W2, W2t);
  embed_kernel<<<NTOK, 256, 0, stream>>>(x, emb, hbf);

  for (int l = 0; l < NLAYERS; ++l) {
    // QKV: [32768,512] x [1536,512]^T -> dense [32768,1536] f16
    gemm128<0><<<dim3(12, NTOK/128), 256, 0, stream>>>(
        hbf, Wqkv_t + (size_t)l*1536*512, biasq + (size_t)l*1536, big, 512, 1536);
    attn_kernel<<<BATCH*NHEADS/4, 256, 0, stream>>>(big, attnb);
    resid_ln<false><<<BATCH, 1024, 0, stream>>>(attnb, hbf, nullptr);
    // FF in two half-M chunks (16384 rows), inner buffer reuses `big`
    for (int c = 0; c < 2; ++c) {
      gemm128<1><<<dim3(16, 128), 256, 0, stream>>>(
          hbf + (size_t)c*16384*512, W1t + (size_t)l*INNER*512, b1 + (size_t)l*INNER,
          big, 512, INNER);
      gemm128<0><<<dim3(4, 128), 256, 0, stream>>>(
          big, W2t + (size_t)l*512*INNER, b2 + (size_t)l*512,
          attnb + (size_t)c*16384*512, INNER, 512);
    }
    if (l == NLAYERS-1) {
      resid_ln<true><<<BATCH, 1024, 0, stream>>>(attnb, hbf, h);
    } else {
      resid_ln<false><<<BATCH, 1024, 0, stream>>>(attnb, hbf, nullptr);
    }
  }
}

// Round 5
// 1878.534 us; speedup vs baseline: 1.7302x; 1.1293x over previous
//
#include <hip/hip_runtime.h>
#include <stdint.h>

#define NLAYERS 6
#define DMODEL  512
#define NHEADS  8
#define HDIM    64
#define INNER   2048
#define SEQ     128
#define BATCH   256
#define NTOK    (BATCH*SEQ)

typedef __attribute__((ext_vector_type(4))) float f32x4;
typedef __attribute__((ext_vector_type(8))) _Float16 hfrag;

typedef const __attribute__((address_space(1))) void* gas1p;
typedef __attribute__((address_space(3))) void* las3p;

__device__ __forceinline__ void load_lds16(const void* g, void* l) {
  __builtin_amdgcn_global_load_lds((gas1p)(uintptr_t)g, (las3p)(uint32_t)(uintptr_t)l, 16, 0, 0);
}

__device__ __forceinline__ ushort f2h(float f) {
  return __builtin_bit_cast(ushort, (_Float16)f);
}
__device__ __forceinline__ float h2f(ushort u) {
  return (float)__builtin_bit_cast(_Float16, u);
}

__device__ __forceinline__ f32x4 mfma16(hfrag a, hfrag b, f32x4 c) {
  return __builtin_amdgcn_mfma_f32_16x16x32_f16(a, b, c, 0, 0, 0);
}

// ---------------- weight prep (f32 -> f16, transposed to [N][K]) ----------------

__global__ void prep_qkv(const float* __restrict__ Wq, const float* __restrict__ Wk,
                         const float* __restrict__ Wv, const float* __restrict__ bq,
                         const float* __restrict__ bk, const float* __restrict__ bv,
                         ushort* __restrict__ Wt, float* __restrict__ biasq) {
  int idx = blockIdx.x*256 + threadIdx.x;
  if (idx >= NLAYERS*1536*512) return;
  const int k = idx & 511;
  const int n = (idx >> 9) % 1536;
  const int l = idx / (1536*512);
  const int which = n >> 9, hh = (n >> 6) & 7, e = n & 63;
  const float* W = (which == 0) ? Wq : ((which == 1) ? Wk : Wv);
  Wt[idx] = f2h(W[(((size_t)l*NHEADS + hh)*DMODEL + k)*HDIM + e]);
  if (k == 0) {
    const float* bb = (which == 0) ? bq : ((which == 1) ? bk : bv);
    biasq[l*1536 + n] = bb[((size_t)l*NHEADS + hh)*HDIM + e];
  }
}

__global__ void prep_w1(const float* __restrict__ W1, ushort* __restrict__ W1t) {
  int idx = blockIdx.x*256 + threadIdx.x;
  if (idx >= NLAYERS*INNER*512) return;
  const int k = idx & 511;
  const int n = (idx >> 9) % INNER;
  const int l = idx / (INNER*512);
  W1t[idx] = f2h(W1[((size_t)l*DMODEL + k)*INNER + n]);
}

__global__ void prep_w2(const float* __restrict__ W2, ushort* __restrict__ W2t) {
  int idx = blockIdx.x*256 + threadIdx.x;
  if (idx >= NLAYERS*512*INNER) return;
  const int k = idx & 2047;
  const int n = (idx >> 11) & 511;
  const int l = idx / (512*INNER);
  W2t[idx] = f2h(W2[((size_t)l*INNER + k)*DMODEL + n]);
}

// ---------------- embedding + positional encoding (f16 residual stream) ----------------

__global__ void embed_kernel(const int* __restrict__ x, const float* __restrict__ emb,
                             ushort* __restrict__ hb) {
  const int t = blockIdx.x;       // token 0..32767
  const int i = threadIdx.x;      // pair 0..255
  const int s = t & (SEQ-1);
  const int tok = x[t];
  const float freq = expf(-(float)i * (9.210340371976184f / 256.0f)); // 10000^(-i/256)
  const float th = (float)s * freq;
  const float sn = sinf(th), cs = cosf(th);
  const size_t base = (size_t)t*DMODEL;
  const float v0 = emb[(size_t)tok*DMODEL + 2*i]     + sn;
  const float v1 = emb[(size_t)tok*DMODEL + 2*i + 1] + cs;
  *(uint*)(hb + base + 2*i) = (uint)f2h(v0) | ((uint)f2h(v1) << 16);
}

// ---------------- 256x256 tiled f16 MFMA GEMM, 2-phase/K-tile, counted vmcnt ----
// C = A[M,K] @ Bt[N,K]^T. 8 waves (2M x 4N), wave tile 128x64, BK=32.
// LDS ring: 6 slots x 16 KB (3 K-tiles of A16K+B16K). Stage lead-5, vmcnt(6).
// EPI: 0 = bias->f16, 1 = bias+relu->f16

template<int K, int EPI>
__global__ __launch_bounds__(512, 2) void gemm256(
    const ushort* __restrict__ A, const ushort* __restrict__ Bt,
    const float* __restrict__ bias, ushort* __restrict__ outb,
    const int ldc, const int nbn) {
  __shared__ __align__(16) char lds[98304];
  constexpr int NKT = K / 32;
  constexpr int NG  = 2 * NKT;
  const int t = threadIdx.x;
  const int lane = t & 63, w = t >> 6;
  const int wr = w >> 2, wc = w & 3;
  // XCD-chunked block swizzle (gridDim.x % 8 == 0 for all our launches)
  const int cpx = (int)gridDim.x >> 3;
  const int wg  = ((int)blockIdx.x & 7) * cpx + ((int)blockIdx.x >> 3);
  const int bm = wg / nbn, bn = wg % nbn;

  const int fr = lane & 15;
  const int accA = (((lane >> 4) ^ (fr & 3)) << 4);   // swizzled 16B-chunk byte offset

  // bias prefetch + anchor (keeps loop-time vmcnt counting exact)
  float bias_r[4];
  #pragma unroll
  for (int n = 0; n < 4; ++n) bias_r[n] = bias[bn*256 + wc*64 + n*16 + fr];
  asm volatile("" : "+v"(bias_r[0]), "+v"(bias_r[1]), "+v"(bias_r[2]), "+v"(bias_r[3]));

  // staging addressing: thread t -> row t>>2 (0..127), chunk (t&3)^swz; 2 groups of 128 rows
  const int srow = t >> 2;
  const int scc  = (t & 3) ^ (srow & 3);
  const ushort* aSrc = A  + ((size_t)bm*256 + srow)*K + scc*8;
  const ushort* bSrc = Bt + ((size_t)bn*256 + srow)*K + scc*8;

  auto stage_g = [&](int g) {
    const int kt = g >> 1;
    const ushort* src = ((g & 1) ? bSrc : aSrc) + kt*32;
    char* dst = lds + (g % 6)*16384 + t*16;
    load_lds16(src, dst);
    load_lds16(src + (size_t)128*K, dst + 8192);
  };

  f32x4 acc[8][4] = {};

  // prologue: stage halves g=0..4 (A0,B0,A1,B1,A2), wait for K-tile 0
  stage_g(0); stage_g(1); stage_g(2); stage_g(3); stage_g(4);
  asm volatile("s_waitcnt vmcnt(6)" ::: "memory");
  __builtin_amdgcn_s_barrier();

  #pragma unroll 1
  for (int kt = 0; kt < NKT; ++kt) {
    const int Ab = ((2*kt) % 6) * 16384;
    hfrag a[8], b[4];
    #pragma unroll
    for (int m = 0; m < 8; ++m)
      a[m] = *(const hfrag*)(lds + Ab + (wr*128 + m*16 + fr)*64 + accA);
    #pragma unroll
    for (int n = 0; n < 4; ++n)
      b[n] = *(const hfrag*)(lds + Ab + 16384 + (wc*64 + n*16 + fr)*64 + accA);
    if (2*kt + 5 < NG) stage_g(2*kt + 5);
    __builtin_amdgcn_s_barrier();
    __builtin_amdgcn_s_setprio(1);
    #pragma unroll
    for (int m = 0; m < 4; ++m)
      #pragma unroll
      for (int n = 0; n < 4; ++n)
        acc[m][n] = mfma16(a[m], b[n], acc[m][n]);
    __builtin_amdgcn_s_setprio(0);
    __builtin_amdgcn_s_barrier();
    // odd phase
    if (2*kt + 6 < NG) stage_g(2*kt + 6);
    __builtin_amdgcn_s_barrier();
    __builtin_amdgcn_s_setprio(1);
    #pragma unroll
    for (int m = 4; m < 8; ++m)
      #pragma unroll
      for (int n = 0; n < 4; ++n)
        acc[m][n] = mfma16(a[m], b[n], acc[m][n]);
    __builtin_amdgcn_s_setprio(0);
    if (kt < NKT - 3) {
      asm volatile("s_waitcnt vmcnt(6)" ::: "memory");
    } else if (kt == NKT - 3) {
      asm volatile("s_waitcnt vmcnt(4)" ::: "memory");
    } else if (kt == NKT - 2) {
      asm volatile("s_waitcnt vmcnt(0)" ::: "memory");
    }
    __builtin_amdgcn_s_barrier();
  }

  // epilogue
  #pragma unroll
  for (int m = 0; m < 8; ++m) {
    #pragma unroll
    for (int n = 0; n < 4; ++n) {
      #pragma unroll
      for (int r4 = 0; r4 < 4; ++r4) {
        const int row = bm*256 + wr*128 + m*16 + ((lane >> 4) << 2) + r4;
        const int col = bn*256 + wc*64 + n*16 + fr;
        float v = acc[m][n][r4] + bias_r[n];
        if constexpr (EPI == 1) v = fmaxf(v, 0.0f);
        outb[(size_t)row*ldc + col] = f2h(v);
      }
    }
  }
}

// ---------------- attention (no softmax): out = q @ (scale * k^T v) ----------------
// qkv dense layout [token][1536] (q | k | v, each [h][e]).
// one wave per (b,h); 4 per block; per-wave LDS transpose of k,v chunks.

__global__ __launch_bounds__(256) void attn_kernel(
    const ushort* __restrict__ qkv, ushort* __restrict__ outb) {
  __shared__ __align__(16) ushort wbuf[4][8192];   // 16KB per wave
  const int tid = threadIdx.x;
  const int w = tid >> 6, lane = tid & 63;
  const int bh = blockIdx.x*4 + w;
  const int b = bh >> 3, h = bh & 7;
  const ushort* tokbase = qkv + (size_t)b*SEQ*1536;
  ushort* lds = &wbuf[w][0];
  ushort* kch = lds;            // swizzled [32][64]
  ushort* vch = lds + 2048;

  // ktv[e1][e2] = sum_s k[s][e1] * v[s][e2]
  f32x4 acc1[4][4] = {};
  #pragma unroll 1
  for (int sb = 0; sb < 4; ++sb) {
    const int s0 = sb*32;
    const int sr = lane >> 1;
    #pragma unroll
    for (int i = 0; i < 4; ++i) {
      const int cc  = i*2 + (lane & 1);
      const int ccs = cc ^ (sr & 7);               // bank-spread swizzle (16B units)
      const ushort* g = tokbase + (size_t)(s0+sr)*1536 + h*64 + cc*8;
      *(uint4*)(kch + sr*64 + ccs*8) = *(const uint4*)(g + 512);
      *(uint4*)(vch + sr*64 + ccs*8) = *(const uint4*)(g + 1024);
    }
    hfrag ak[4], av[4];
    #pragma unroll
    for (int m = 0; m < 4; ++m) {
      const int e1 = m*16 + (lane & 15);
      const int ccb = e1 >> 3, el = e1 & 7;
      #pragma unroll
      for (int j = 0; j < 8; ++j) {
        const int s = (lane >> 4)*8 + j;
        ak[m][j] = __builtin_bit_cast(_Float16, kch[s*64 + ((ccb ^ (s & 7))*8) + el]);
        av[m][j] = __builtin_bit_cast(_Float16, vch[s*64 + ((ccb ^ (s & 7))*8) + el]);
      }
    }
    #pragma unroll
    for (int m = 0; m < 4; ++m)
      #pragma unroll
      for (int n = 0; n < 4; ++n)
        acc1[m][n] = mfma16(ak[m], av[n], acc1[m][n]);
  }

  // store scale*ktv transposed into per-wave LDS: tv[e2][e1], padded rows (72)
  ushort* tv = lds;
  #pragma unroll
  for (int m = 0; m < 4; ++m)
    #pragma unroll
    for (int n = 0; n < 4; ++n)
      #pragma unroll
      for (int r4 = 0; r4 < 4; ++r4) {
        const int e1 = m*16 + (lane >> 4)*4 + r4;
        const int e2 = n*16 + (lane & 15);
        tv[e2*72 + e1] = f2h(acc1[m][n][r4] * 0.125f);
      }

  // attn[s][e2] = sum_e1 q[s][e1] * ktv[e1][e2]
  f32x4 acc2[8][4] = {};
  #pragma unroll
  for (int eb = 0; eb < 2; ++eb) {
    const int e1b = eb*32 + (lane >> 4)*8;
    hfrag aq[8], bk2[4];
    #pragma unroll
    for (int m = 0; m < 8; ++m) {
      const int s = m*16 + (lane & 15);
      aq[m] = *(const hfrag*)(tokbase + (size_t)s*1536 + h*64 + e1b);
    }
    #pragma unroll
    for (int n = 0; n < 4; ++n) {
      const int e2 = n*16 + (lane & 15);
      bk2[n] = *(const hfrag*)(tv + e2*72 + e1b);
    }
    #pragma unroll
    for (int m = 0; m < 8; ++m)
      #pragma unroll
      for (int n = 0; n < 4; ++n)
        acc2[m][n] = mfma16(aq[m], bk2[n], acc2[m][n]);
  }
  #pragma unroll
  for (int m = 0; m < 8; ++m)
    #pragma unroll
    for (int n = 0; n < 4; ++n)
      #pragma unroll
      for (int r4 = 0; r4 < 4; ++r4) {
        const int s  = m*16 + (lane >> 4)*4 + r4;
        const int e2 = n*16 + (lane & 15);
        outb[((size_t)b*SEQ + s)*DMODEL + h*HDIM + e2] = f2h(acc2[m][n][r4]);
      }
}

// ---------------- residual + LayerNorm over (S,D) per batch sample ----------------
// f16 residual stream: hb = LN(hb + delta). Cache kept as PACKED f16 (32 VGPRs).
// FINAL: also write f32 to hf (the harness output).

template<bool FINAL>
__global__ __launch_bounds__(1024) void resid_ln(
    const ushort* __restrict__ delta, ushort* __restrict__ hb, float* __restrict__ hf) {
  const int b = blockIdx.x;
  const size_t base = (size_t)b * (SEQ*DMODEL);
  uint4 cache[8];                       // 64 halves packed
  float s = 0.f, q = 0.f;
  #pragma unroll
  for (int j = 0; j < 8; ++j) {
    const size_t idx = base + (size_t)j*8192 + threadIdx.x*8;
    const uint4 hv = *(const uint4*)(hb + idx);
    const uint4 dv = *(const uint4*)(delta + idx);
    uint4 cv;
    #pragma unroll
    for (int c = 0; c < 4; ++c) {
      const uint hu = (&hv.x)[c], du = (&dv.x)[c];
      const float v0 = h2f((ushort)(hu & 0xffffu)) + h2f((ushort)(du & 0xffffu));
      const float v1 = h2f((ushort)(hu >> 16))     + h2f((ushort)(du >> 16));
      s += v0 + v1; q += v0*v0 + v1*v1;
      (&cv.x)[c] = (uint)f2h(v0) | ((uint)f2h(v1) << 16);
    }
    cache[j] = cv;
  }
  #pragma unroll
  for (int off = 32; off > 0; off >>= 1) {
    s += __shfl_down(s, off);
    q += __shfl_down(q, off);
  }
  __shared__ float ws_[16], wq_[16];
  __shared__ float stat[2];
  const int w = threadIdx.x >> 6, lane = threadIdx.x & 63;
  if (lane == 0) { ws_[w] = s; wq_[w] = q; }
  __syncthreads();
  if (threadIdx.x == 0) {
    float S = 0.f, Q = 0.f;
    #pragma unroll
    for (int i2 = 0; i2 < 16; ++i2) { S += ws_[i2]; Q += wq_[i2]; }
    const float mean = S * (1.0f/65536.0f);
    const float var  = Q * (1.0f/65536.0f) - mean*mean;
    stat[0] = mean; stat[1] = rsqrtf(var + 1e-5f);
  }
  __syncthreads();
  const float mean = stat[0], rstd = stat[1];
  #pragma unroll
  for (int j = 0; j < 8; ++j) {
    const size_t idx = base + (size_t)j*8192 + threadIdx.x*8;
    const uint4 cv = cache[j];
    if constexpr (FINAL) {
      #pragma unroll
      for (int c = 0; c < 4; ++c) {
        const uint u = (&cv.x)[c];
        const float o0 = (h2f((ushort)(u & 0xffffu)) - mean) * rstd;
        const float o1 = (h2f((ushort)(u >> 16))     - mean) * rstd;
        *(float2*)(hf + idx + c*2) = make_float2(o0, o1);
      }
    } else {
      uint4 ov;
      #pragma unroll
      for (int c = 0; c < 4; ++c) {
        const uint u = (&cv.x)[c];
        const float o0 = (h2f((ushort)(u & 0xffffu)) - mean) * rstd;
        const float o1 = (h2f((ushort)(u >> 16))     - mean) * rstd;
        (&ov.x)[c] = (uint)f2h(o0) | ((uint)f2h(o1) << 16);
      }
      *(uint4*)(hb + idx) = ov;
    }
  }
}

// ---------------- driver ----------------

extern "C" void kernel_launch(void* const* d_in, const int* in_sizes, int n_in,
                              void* d_out, int out_size, void* d_ws, size_t ws_size,
                              hipStream_t stream) {
  const int*   x   = (const int*)d_in[0];
  const float* emb = (const float*)d_in[1];
  const float* Wq  = (const float*)d_in[2];
  const float* bq  = (const float*)d_in[3];
  const float* Wk  = (const float*)d_in[4];
  const float* bk  = (const float*)d_in[5];
  const float* Wv  = (const float*)d_in[6];
  const float* bv  = (const float*)d_in[7];
  const float* W1  = (const float*)d_in[8];
  const float* b1  = (const float*)d_in[9];
  const float* W2  = (const float*)d_in[10];
  const float* b2  = (const float*)d_in[11];
  float* h = (float*)d_out;

  char* p = (char*)d_ws;
  size_t off = 0;
  auto alloc = [&](size_t bytes) { char* r = p + off; off += (bytes + 255) & ~(size_t)255; return r; };
  ushort* Wqkv_t = (ushort*)alloc((size_t)NLAYERS*1536*512*2);
  ushort* W1t    = (ushort*)alloc((size_t)NLAYERS*INNER*512*2);
  ushort* W2t    = (ushort*)alloc((size_t)NLAYERS*512*INNER*2);
  float*  biasq  = (float*)alloc((size_t)NLAYERS*1536*4);
  ushort* hbf    = (ushort*)alloc((size_t)NTOK*512*2);
  ushort* big    = (ushort*)alloc((size_t)NTOK*2048*2);  // qkv (1536) / FF inner (2048) buffer
  ushort* attnb  = (ushort*)alloc((size_t)NTOK*512*2);   // attn-out / ff2-out (f16 delta)

  prep_qkv<<<(NLAYERS*1536*512 + 255)/256, 256, 0, stream>>>(Wq, Wk, Wv, bq, bk, bv, Wqkv_t, biasq);
  prep_w1<<<(NLAYERS*INNER*512 + 255)/256, 256, 0, stream>>>(W1, W1t);
  prep_w2<<<(NLAYERS*512*INNER + 255)/256, 256, 0, stream>>>(W2, W2t);
  embed_kernel<<<NTOK, 256, 0, stream>>>(x, emb, hbf);

  for (int l = 0; l < NLAYERS; ++l) {
    // QKV: [32768,512] x [1536,512]^T -> dense [32768,1536] f16
    gemm256<512,0><<<768, 512, 0, stream>>>(
        hbf, Wqkv_t + (size_t)l*1536*512, biasq + (size_t)l*1536, big, 1536, 6);
    attn_kernel<<<BATCH*NHEADS/4, 256, 0, stream>>>(big, attnb);
    resid_ln<false><<<BATCH, 1024, 0, stream>>>(attnb, hbf, nullptr);
    // FF1: [32768,512] x [2048,512]^T -> relu -> big [32768,2048]
    gemm256<512,1><<<1024, 512, 0, stream>>>(
        hbf, W1t + (size_t)l*INNER*512, b1 + (size_t)l*INNER, big, 2048, 8);
    // FF2: [32768,2048] x [512,2048]^T -> attnb [32768,512]
    gemm256<2048,0><<<256, 512, 0, stream>>>(
        big, W2t + (size_t)l*512*INNER, b2 + (size_t)l*512, attnb, 512, 2);
    if (l == NLAYERS-1) {
      resid_ln<true><<<BATCH, 1024, 0, stream>>>(attnb, hbf, h);
    } else {
      resid_ln<false><<<BATCH, 1024, 0, stream>>>(attnb, hbf, nullptr);
    }
  }
}

// Round 6
// 1811.854 us; speedup vs baseline: 1.7939x; 1.0368x over previous
//
#include <hip/hip_runtime.h>
#include <stdint.h>

#define NLAYERS 6
#define DMODEL  512
#define NHEADS  8
#define HDIM    64
#define INNER   2048
#define SEQ     128
#define BATCH   256
#define NTOK    (BATCH*SEQ)

typedef __attribute__((ext_vector_type(4))) float f32x4;
typedef __attribute__((ext_vector_type(8))) _Float16 hfrag;

typedef const __attribute__((address_space(1))) void* gas1p;
typedef __attribute__((address_space(3))) void* las3p;

__device__ __forceinline__ void load_lds16(const void* g, void* l) {
  __builtin_amdgcn_global_load_lds((gas1p)(uintptr_t)g, (las3p)(uint32_t)(uintptr_t)l, 16, 0, 0);
}

__device__ __forceinline__ ushort f2h(float f) {
  return __builtin_bit_cast(ushort, (_Float16)f);
}
__device__ __forceinline__ float h2f(ushort u) {
  return (float)__builtin_bit_cast(_Float16, u);
}

__device__ __forceinline__ f32x4 mfma16(hfrag a, hfrag b, f32x4 c) {
  return __builtin_amdgcn_mfma_f32_16x16x32_f16(a, b, c, 0, 0, 0);
}

// ---------------- weight prep (f32 -> f16, transposed to [N][K]) ----------------

__global__ void prep_qkv(const float* __restrict__ Wq, const float* __restrict__ Wk,
                         const float* __restrict__ Wv, const float* __restrict__ bq,
                         const float* __restrict__ bk, const float* __restrict__ bv,
                         ushort* __restrict__ Wt, float* __restrict__ biasq) {
  int idx = blockIdx.x*256 + threadIdx.x;
  if (idx >= NLAYERS*1536*512) return;
  const int k = idx & 511;
  const int n = (idx >> 9) % 1536;
  const int l = idx / (1536*512);
  const int which = n >> 9, hh = (n >> 6) & 7, e = n & 63;
  const float* W = (which == 0) ? Wq : ((which == 1) ? Wk : Wv);
  Wt[idx] = f2h(W[(((size_t)l*NHEADS + hh)*DMODEL + k)*HDIM + e]);
  if (k == 0) {
    const float* bb = (which == 0) ? bq : ((which == 1) ? bk : bv);
    biasq[l*1536 + n] = bb[((size_t)l*NHEADS + hh)*HDIM + e];
  }
}

__global__ void prep_w1(const float* __restrict__ W1, ushort* __restrict__ W1t) {
  int idx = blockIdx.x*256 + threadIdx.x;
  if (idx >= NLAYERS*INNER*512) return;
  const int k = idx & 511;
  const int n = (idx >> 9) % INNER;
  const int l = idx / (INNER*512);
  W1t[idx] = f2h(W1[((size_t)l*DMODEL + k)*INNER + n]);
}

__global__ void prep_w2(const float* __restrict__ W2, ushort* __restrict__ W2t) {
  int idx = blockIdx.x*256 + threadIdx.x;
  if (idx >= NLAYERS*512*INNER) return;
  const int k = idx & 2047;
  const int n = (idx >> 11) & 511;
  const int l = idx / (512*INNER);
  W2t[idx] = f2h(W2[((size_t)l*INNER + k)*DMODEL + n]);
}

// ---------------- embedding + positional encoding (f16 residual stream) ----------------

__global__ void embed_kernel(const int* __restrict__ x, const float* __restrict__ emb,
                             ushort* __restrict__ hb) {
  const int t = blockIdx.x;       // token 0..32767
  const int i = threadIdx.x;      // pair 0..255
  const int s = t & (SEQ-1);
  const int tok = x[t];
  const float freq = expf(-(float)i * (9.210340371976184f / 256.0f)); // 10000^(-i/256)
  const float th = (float)s * freq;
  const float sn = sinf(th), cs = cosf(th);
  const size_t base = (size_t)t*DMODEL;
  const float v0 = emb[(size_t)tok*DMODEL + 2*i]     + sn;
  const float v1 = emb[(size_t)tok*DMODEL + 2*i + 1] + cs;
  *(uint*)(hb + base + 2*i) = (uint)f2h(v0) | ((uint)f2h(v1) << 16);
}

// ---------------- 256x256 tiled f16 MFMA GEMM, 2-phase/K-tile, counted vmcnt ----
// C = A[M,K] @ Bt[N,K]^T. 8 waves (2M x 4N), wave tile 128x64, BK=32.
// LDS ring: 6 slots x 16 KB (3 K-tiles of A16K+B16K). Stage lead-5, vmcnt(6).
// LDS chunk map: 16B chunk of (row r, kchunk c) at p = r*4 + (c ^ ((r>>1)&3)):
//   bank-start = (r&1)*4 + ((c^((r>>1)&3))&3) -> 8 distinct per 8 lanes (conflict-free).
// EPI: 0 = bias->f16, 1 = bias+relu->f16

template<int K, int EPI>
__global__ __launch_bounds__(512, 2) void gemm256(
    const ushort* __restrict__ A, const ushort* __restrict__ Bt,
    const float* __restrict__ bias, ushort* __restrict__ outb,
    const int ldc, const int nbn) {
  __shared__ __align__(16) char lds[98304];
  constexpr int NKT = K / 32;
  constexpr int NG  = 2 * NKT;
  const int t = threadIdx.x;
  const int lane = t & 63, w = t >> 6;
  const int wr = w >> 2, wc = w & 3;
  // XCD-chunked block swizzle (gridDim.x % 8 == 0 for all our launches)
  const int cpx = (int)gridDim.x >> 3;
  const int wg  = ((int)blockIdx.x & 7) * cpx + ((int)blockIdx.x >> 3);
  const int bm = wg / nbn, bn = wg % nbn;

  const int fr = lane & 15;
  const int cxor = (((lane >> 4) ^ ((fr >> 1) & 3)) << 4);  // bank-spread chunk offset

  // bias prefetch + anchor (keeps loop-time vmcnt counting exact)
  float bias_r[4];
  #pragma unroll
  for (int n = 0; n < 4; ++n) bias_r[n] = bias[bn*256 + wc*64 + n*16 + fr];
  asm volatile("" : "+v"(bias_r[0]), "+v"(bias_r[1]), "+v"(bias_r[2]), "+v"(bias_r[3]));

  // staging: thread t -> row t>>2 (0..127, +128 for 2nd load), kchunk (t&3)^((t>>3)&3)
  const int srow = t >> 2;
  const int scc  = (t & 3) ^ ((t >> 3) & 3);
  const ushort* aSrc = A  + ((size_t)bm*256 + srow)*K + scc*8;
  const ushort* bSrc = Bt + ((size_t)bn*256 + srow)*K + scc*8;

  auto stage_g = [&](int g) {
    const int kt = g >> 1;
    const ushort* src = ((g & 1) ? bSrc : aSrc) + kt*32;
    char* dst = lds + (g % 6)*16384 + t*16;
    load_lds16(src, dst);
    load_lds16(src + (size_t)128*K, dst + 8192);
  };

  f32x4 acc[8][4] = {};

  // prologue: stage halves g=0..4 (A0,B0,A1,B1,A2), wait for K-tile 0
  stage_g(0); stage_g(1); stage_g(2); stage_g(3); stage_g(4);
  asm volatile("s_waitcnt vmcnt(6)" ::: "memory");
  __builtin_amdgcn_s_barrier();

  #pragma unroll 1
  for (int kt = 0; kt < NKT; ++kt) {
    const int Ab = ((2*kt) % 6) * 16384;
    hfrag a[8], b[4];
    #pragma unroll
    for (int m = 0; m < 8; ++m)
      a[m] = *(const hfrag*)(lds + Ab + (wr*128 + m*16 + fr)*64 + cxor);
    #pragma unroll
    for (int n = 0; n < 4; ++n)
      b[n] = *(const hfrag*)(lds + Ab + 16384 + (wc*64 + n*16 + fr)*64 + cxor);
    if (2*kt + 5 < NG) stage_g(2*kt + 5);
    __builtin_amdgcn_s_barrier();
    __builtin_amdgcn_s_setprio(1);
    #pragma unroll
    for (int m = 0; m < 4; ++m)
      #pragma unroll
      for (int n = 0; n < 4; ++n)
        acc[m][n] = mfma16(a[m], b[n], acc[m][n]);
    __builtin_amdgcn_s_setprio(0);
    __builtin_amdgcn_s_barrier();
    // odd phase
    if (2*kt + 6 < NG) stage_g(2*kt + 6);
    __builtin_amdgcn_s_barrier();
    __builtin_amdgcn_s_setprio(1);
    #pragma unroll
    for (int m = 4; m < 8; ++m)
      #pragma unroll
      for (int n = 0; n < 4; ++n)
        acc[m][n] = mfma16(a[m], b[n], acc[m][n]);
    __builtin_amdgcn_s_setprio(0);
    if (kt < NKT - 3) {
      asm volatile("s_waitcnt vmcnt(6)" ::: "memory");
    } else if (kt == NKT - 3) {
      asm volatile("s_waitcnt vmcnt(4)" ::: "memory");
    } else if (kt == NKT - 2) {
      asm volatile("s_waitcnt vmcnt(0)" ::: "memory");
    }
    __builtin_amdgcn_s_barrier();
  }

  // epilogue
  #pragma unroll
  for (int m = 0; m < 8; ++m) {
    #pragma unroll
    for (int n = 0; n < 4; ++n) {
      #pragma unroll
      for (int r4 = 0; r4 < 4; ++r4) {
        const int row = bm*256 + wr*128 + m*16 + ((lane >> 4) << 2) + r4;
        const int col = bn*256 + wc*64 + n*16 + fr;
        float v = acc[m][n][r4] + bias_r[n];
        if constexpr (EPI == 1) v = fmaxf(v, 0.0f);
        outb[(size_t)row*ldc + col] = f2h(v);
      }
    }
  }
}

// ---------------- attention (no softmax): out = q @ (scale * k^T v) ----------------
// qkv dense layout [token][1536] (q | k | v, each [h][e]).
// one wave per (b,h); 4 per block; per-wave LDS transpose of k,v chunks.

__global__ __launch_bounds__(256) void attn_kernel(
    const ushort* __restrict__ qkv, ushort* __restrict__ outb) {
  __shared__ __align__(16) ushort wbuf[4][8192];   // 16KB per wave
  const int tid = threadIdx.x;
  const int w = tid >> 6, lane = tid & 63;
  const int bh = blockIdx.x*4 + w;
  const int b = bh >> 3, h = bh & 7;
  const ushort* tokbase = qkv + (size_t)b*SEQ*1536;
  ushort* lds = &wbuf[w][0];
  ushort* kch = lds;            // swizzled [32][64]
  ushort* vch = lds + 2048;

  // ktv[e1][e2] = sum_s k[s][e1] * v[s][e2]
  f32x4 acc1[4][4] = {};
  #pragma unroll 1
  for (int sb = 0; sb < 4; ++sb) {
    const int s0 = sb*32;
    const int sr = lane >> 1;
    #pragma unroll
    for (int i = 0; i < 4; ++i) {
      const int cc  = i*2 + (lane & 1);
      const int ccs = cc ^ (sr & 7);               // bank-spread swizzle (16B units)
      const ushort* g = tokbase + (size_t)(s0+sr)*1536 + h*64 + cc*8;
      *(uint4*)(kch + sr*64 + ccs*8) = *(const uint4*)(g + 512);
      *(uint4*)(vch + sr*64 + ccs*8) = *(const uint4*)(g + 1024);
    }
    hfrag ak[4], av[4];
    #pragma unroll
    for (int m = 0; m < 4; ++m) {
      const int e1 = m*16 + (lane & 15);
      const int ccb = e1 >> 3, el = e1 & 7;
      #pragma unroll
      for (int j = 0; j < 8; ++j) {
        const int s = (lane >> 4)*8 + j;
        ak[m][j] = __builtin_bit_cast(_Float16, kch[s*64 + ((ccb ^ (s & 7))*8) + el]);
        av[m][j] = __builtin_bit_cast(_Float16, vch[s*64 + ((ccb ^ (s & 7))*8) + el]);
      }
    }
    #pragma unroll
    for (int m = 0; m < 4; ++m)
      #pragma unroll
      for (int n = 0; n < 4; ++n)
        acc1[m][n] = mfma16(ak[m], av[n], acc1[m][n]);
  }

  // store scale*ktv transposed into per-wave LDS: tv[e2][e1], padded rows (72)
  ushort* tv = lds;
  #pragma unroll
  for (int m = 0; m < 4; ++m)
    #pragma unroll
    for (int n = 0; n < 4; ++n)
      #pragma unroll
      for (int r4 = 0; r4 < 4; ++r4) {
        const int e1 = m*16 + (lane >> 4)*4 + r4;
        const int e2 = n*16 + (lane & 15);
        tv[e2*72 + e1] = f2h(acc1[m][n][r4] * 0.125f);
      }

  // attn[s][e2] = sum_e1 q[s][e1] * ktv[e1][e2]
  f32x4 acc2[8][4] = {};
  #pragma unroll
  for (int eb = 0; eb < 2; ++eb) {
    const int e1b = eb*32 + (lane >> 4)*8;
    hfrag aq[8], bk2[4];
    #pragma unroll
    for (int m = 0; m < 8; ++m) {
      const int s = m*16 + (lane & 15);
      aq[m] = *(const hfrag*)(tokbase + (size_t)s*1536 + h*64 + e1b);
    }
    #pragma unroll
    for (int n = 0; n < 4; ++n) {
      const int e2 = n*16 + (lane & 15);
      bk2[n] = *(const hfrag*)(tv + e2*72 + e1b);
    }
    #pragma unroll
    for (int m = 0; m < 8; ++m)
      #pragma unroll
      for (int n = 0; n < 4; ++n)
        acc2[m][n] = mfma16(aq[m], bk2[n], acc2[m][n]);
  }
  #pragma unroll
  for (int m = 0; m < 8; ++m)
    #pragma unroll
    for (int n = 0; n < 4; ++n)
      #pragma unroll
      for (int r4 = 0; r4 < 4; ++r4) {
        const int s  = m*16 + (lane >> 4)*4 + r4;
        const int e2 = n*16 + (lane & 15);
        outb[((size_t)b*SEQ + s)*DMODEL + h*HDIM + e2] = f2h(acc2[m][n][r4]);
      }
}

// ---------------- residual + LayerNorm over (S,D) per batch sample ----------------
// f16 residual stream: hb = LN(hb + delta). Cache kept as PACKED f16 (32 VGPRs).
// FINAL: also write f32 to hf (the harness output).

template<bool FINAL>
__global__ __launch_bounds__(1024) void resid_ln(
    const ushort* __restrict__ delta, ushort* __restrict__ hb, float* __restrict__ hf) {
  const int b = blockIdx.x;
  const size_t base = (size_t)b * (SEQ*DMODEL);
  uint4 cache[8];                       // 64 halves packed
  float s = 0.f, q = 0.f;
  #pragma unroll
  for (int j = 0; j < 8; ++j) {
    const size_t idx = base + (size_t)j*8192 + threadIdx.x*8;
    const uint4 hv = *(const uint4*)(hb + idx);
    const uint4 dv = *(const uint4*)(delta + idx);
    uint4 cv;
    #pragma unroll
    for (int c = 0; c < 4; ++c) {
      const uint hu = (&hv.x)[c], du = (&dv.x)[c];
      const float v0 = h2f((ushort)(hu & 0xffffu)) + h2f((ushort)(du & 0xffffu));
      const float v1 = h2f((ushort)(hu >> 16))     + h2f((ushort)(du >> 16));
      s += v0 + v1; q += v0*v0 + v1*v1;
      (&cv.x)[c] = (uint)f2h(v0) | ((uint)f2h(v1) << 16);
    }
    cache[j] = cv;
  }
  #pragma unroll
  for (int off = 32; off > 0; off >>= 1) {
    s += __shfl_down(s, off);
    q += __shfl_down(q, off);
  }
  __shared__ float ws_[16], wq_[16];
  __shared__ float stat[2];
  const int w = threadIdx.x >> 6, lane = threadIdx.x & 63;
  if (lane == 0) { ws_[w] = s; wq_[w] = q; }
  __syncthreads();
  if (threadIdx.x == 0) {
    float S = 0.f, Q = 0.f;
    #pragma unroll
    for (int i2 = 0; i2 < 16; ++i2) { S += ws_[i2]; Q += wq_[i2]; }
    const float mean = S * (1.0f/65536.0f);
    const float var  = Q * (1.0f/65536.0f) - mean*mean;
    stat[0] = mean; stat[1] = rsqrtf(var + 1e-5f);
  }
  __syncthreads();
  const float mean = stat[0], rstd = stat[1];
  #pragma unroll
  for (int j = 0; j < 8; ++j) {
    const size_t idx = base + (size_t)j*8192 + threadIdx.x*8;
    const uint4 cv = cache[j];
    if constexpr (FINAL) {
      #pragma unroll
      for (int c = 0; c < 4; ++c) {
        const uint u = (&cv.x)[c];
        const float o0 = (h2f((ushort)(u & 0xffffu)) - mean) * rstd;
        const float o1 = (h2f((ushort)(u >> 16))     - mean) * rstd;
        *(float2*)(hf + idx + c*2) = make_float2(o0, o1);
      }
    } else {
      uint4 ov;
      #pragma unroll
      for (int c = 0; c < 4; ++c) {
        const uint u = (&cv.x)[c];
        const float o0 = (h2f((ushort)(u & 0xffffu)) - mean) * rstd;
        const float o1 = (h2f((ushort)(u >> 16))     - mean) * rstd;
        (&ov.x)[c] = (uint)f2h(o0) | ((uint)f2h(o1) << 16);
      }
      *(uint4*)(hb + idx) = ov;
    }
  }
}

// ---------------- driver ----------------

extern "C" void kernel_launch(void* const* d_in, const int* in_sizes, int n_in,
                              void* d_out, int out_size, void* d_ws, size_t ws_size,
                              hipStream_t stream) {
  const int*   x   = (const int*)d_in[0];
  const float* emb = (const float*)d_in[1];
  const float* Wq  = (const float*)d_in[2];
  const float* bq  = (const float*)d_in[3];
  const float* Wk  = (const float*)d_in[4];
  const float* bk  = (const float*)d_in[5];
  const float* Wv  = (const float*)d_in[6];
  const float* bv  = (const float*)d_in[7];
  const float* W1  = (const float*)d_in[8];
  const float* b1  = (const float*)d_in[9];
  const float* W2  = (const float*)d_in[10];
  const float* b2  = (const float*)d_in[11];
  float* h = (float*)d_out;

  char* p = (char*)d_ws;
  size_t off = 0;
  auto alloc = [&](size_t bytes) { char* r = p + off; off += (bytes + 255) & ~(size_t)255; return r; };
  ushort* Wqkv_t = (ushort*)alloc((size_t)NLAYERS*1536*512*2);
  ushort* W1t    = (ushort*)alloc((size_t)NLAYERS*INNER*512*2);
  ushort* W2t    = (ushort*)alloc((size_t)NLAYERS*512*INNER*2);
  float*  biasq  = (float*)alloc((size_t)NLAYERS*1536*4);
  ushort* hbf    = (ushort*)alloc((size_t)NTOK*512*2);
  ushort* big    = (ushort*)alloc((size_t)NTOK*2048*2);  // qkv (1536) / FF inner (2048) buffer
  ushort* attnb  = (ushort*)alloc((size_t)NTOK*512*2);   // attn-out / ff2-out (f16 delta)

  prep_qkv<<<(NLAYERS*1536*512 + 255)/256, 256, 0, stream>>>(Wq, Wk, Wv, bq, bk, bv, Wqkv_t, biasq);
  prep_w1<<<(NLAYERS*INNER*512 + 255)/256, 256, 0, stream>>>(W1, W1t);
  prep_w2<<<(NLAYERS*512*INNER + 255)/256, 256, 0, stream>>>(W2, W2t);
  embed_kernel<<<NTOK, 256, 0, stream>>>(x, emb, hbf);

  for (int l = 0; l < NLAYERS; ++l) {
    // QKV: [32768,512] x [1536,512]^T -> dense [32768,1536] f16
    gemm256<512,0><<<768, 512, 0, stream>>>(
        hbf, Wqkv_t + (size_t)l*1536*512, biasq + (size_t)l*1536, big, 1536, 6);
    attn_kernel<<<BATCH*NHEADS/4, 256, 0, stream>>>(big, attnb);
    resid_ln<false><<<BATCH, 1024, 0, stream>>>(attnb, hbf, nullptr);
    // FF1: [32768,512] x [2048,512]^T -> relu -> big [32768,2048]
    gemm256<512,1><<<1024, 512, 0, stream>>>(
        hbf, W1t + (size_t)l*INNER*512, b1 + (size_t)l*INNER, big, 2048, 8);
    // FF2: [32768,2048] x [512,2048]^T -> attnb [32768,512]
    gemm256<2048,0><<<256, 512, 0, stream>>>(
        big, W2t + (size_t)l*512*INNER, b2 + (size_t)l*512, attnb, 512, 2);
    if (l == NLAYERS-1) {
      resid_ln<true><<<BATCH, 1024, 0, stream>>>(attnb, hbf, h);
    } else {
      resid_ln<false><<<BATCH, 1024, 0, stream>>>(attnb, hbf, nullptr);
    }
  }
}